// Round 7
// baseline (1863.150 us; speedup 1.0000x reference)
//
#include <hip/hip_runtime.h>
#include <stdint.h>

typedef unsigned short u16;
typedef float f32x4 __attribute__((ext_vector_type(4)));
typedef __bf16 bf16x8 __attribute__((ext_vector_type(8)));

#define B_ 4096
#define D_ 2048
#define U_ 2048
#define K_ 4096   // D + U
#define N_ 8192   // 4*U
#define NT_ 128   // K/32 K-tiles

__device__ __forceinline__ u16 f32_bf16(float f) {
  uint32_t u = __float_as_uint(f);
  u += 0x7FFFu + ((u >> 16) & 1u);
  return (u16)(u >> 16);
}
__device__ __forceinline__ float hsig(float x) {
  return fminf(fmaxf(0.2f * x + 0.5f, 0.0f), 1.0f);
}
__device__ __forceinline__ float ftanh(float x) {
  x = fminf(fmaxf(x, -15.0f), 15.0f);
  float e = __expf(2.0f * x);
  return (e - 1.0f) / (e + 1.0f);
}
__device__ __forceinline__ void gload16(const void* g, void* l) {
  __builtin_amdgcn_global_load_lds(
      (const __attribute__((address_space(1))) void*)g,
      (__attribute__((address_space(3))) void*)l,
      16, 0, 0);
}

// ---- cast A = [inputs | h_tm1] -> bf16 [4096][4096] ----
__global__ __launch_bounds__(256) void cast_a(const float* __restrict__ x,
                                              const float* __restrict__ h,
                                              u16* __restrict__ A) {
  int c = blockIdx.x * 256 + threadIdx.x;
  int m = c >> 9;
  int kc = (c & 511) << 3;
  const float* src = (kc < D_) ? (x + (size_t)m * D_ + kc)
                               : (h + (size_t)m * U_ + (kc - D_));
  float4 v0 = ((const float4*)src)[0];
  float4 v1 = ((const float4*)src)[1];
  u16 o[8] = { f32_bf16(v0.x), f32_bf16(v0.y), f32_bf16(v0.z), f32_bf16(v0.w),
               f32_bf16(v1.x), f32_bf16(v1.y), f32_bf16(v1.z), f32_bf16(v1.w) };
  *(uint4*)(A + (size_t)c * 8) = *(const uint4*)o;
}

// ---- cast + transpose + gate-interleave W -> Wt[n'][k] bf16 [8192][4096] ----
// n' = ublk*64 + g*16 + ul  where u = ublk*16 + ul, original col n = g*2048 + u
__global__ __launch_bounds__(256) void cast_wt(const float* __restrict__ kern,
                                               const float* __restrict__ rker,
                                               u16* __restrict__ Wt) {
  __shared__ u16 sW[64][68];
  const int t = threadIdx.x;
  const int bx = blockIdx.x;   // ublk 0..127
  const int by = blockIdx.y;   // k block 0..63
  const int k0 = by * 64;
  const float* src = (k0 < D_) ? kern : rker;
  const int krow0 = (k0 < D_) ? k0 : (k0 - D_);
#pragma unroll
  for (int i = 0; i < 4; ++i) {
    int c = i * 256 + t;
    int kl = c >> 4;
    int nq = c & 15;
    int g  = nq >> 2;
    int ul = (nq & 3) << 2;
    int n  = g * U_ + bx * 16 + ul;
    float4 v = *(const float4*)(src + (size_t)(krow0 + kl) * N_ + n);
    u16 p[4] = { f32_bf16(v.x), f32_bf16(v.y), f32_bf16(v.z), f32_bf16(v.w) };
    *(ushort4*)&sW[kl][g * 16 + ul] = *(const ushort4*)p;
  }
  __syncthreads();
#pragma unroll
  for (int j = 0; j < 2; ++j) {
    int c2 = j * 256 + t;
    int nl = c2 >> 3;
    int kc = c2 & 7;
    u16 p[8];
#pragma unroll
    for (int jj = 0; jj < 8; ++jj) p[jj] = sW[kc * 8 + jj][nl];
    *(uint4*)(Wt + ((size_t)bx * 64 + nl) * K_ + k0 + kc * 8) = *(const uint4*)p;
  }
}

// ===== 256x256 GEMM: 4-parity BK=32, MFMA/ds_read interleaved per phase =====
// LDS: 4 parities x (A[256][32] 16K + B[256][32] 16K) = 128 KiB.
// phys_chunk = logical ^ ((row>>1)&3): measured 0-conflict (round 3/6).
// Phase p: [stage tile p+2 -> parity (p+2)%4] [VMW(4): drain stage(p-1) ->
// parity (p+1) ready] [lgkm(0): drain reads issued at p-1] [barrier]
// [32 MFMA on regs(tile p) interleaved with 12 ds_reads of parity (p+1),
//  WAR-rotated into the same registers].  Safety: re-stage of parity q
// (issued at q-2) follows barrier(q-3), which follows every wave's lgkm(0)
// drain of its parity-q reads (issued q-4, drained q-3 pre-barrier).
#define LDSA(par) ((par) * 32768)
#define LDSB(par) ((par) * 32768 + 16384)

#define STAGE4(par, t) do { \
  const u16* ga_ = Ab + (size_t)grow * K_ + (t) * 32 + gch8; \
  const u16* gb_ = Bb + (size_t)grow * K_ + (t) * 32 + gch8; \
  char* la_ = ldsc + LDSA(par) + wid * 1024; \
  char* lb_ = ldsc + LDSB(par) + wid * 1024; \
  gload16(ga_, la_); \
  gload16(ga_ + (size_t)128 * K_, la_ + 8192); \
  gload16(gb_, lb_); \
  gload16(gb_ + (size_t)128 * K_, lb_ + 8192); \
} while (0)

#define VMW(n) asm volatile("s_waitcnt vmcnt(" #n ")" ::: "memory")
#define MFMA16 __builtin_amdgcn_mfma_f32_16x16x32_bf16

#define G8(mA, mB) \
  acc[mA][0] = MFMA16(av[mA], bv[0], acc[mA][0], 0, 0, 0); \
  acc[mA][1] = MFMA16(av[mA], bv[1], acc[mA][1], 0, 0, 0); \
  acc[mA][2] = MFMA16(av[mA], bv[2], acc[mA][2], 0, 0, 0); \
  acc[mA][3] = MFMA16(av[mA], bv[3], acc[mA][3], 0, 0, 0); \
  acc[mB][0] = MFMA16(av[mB], bv[0], acc[mB][0], 0, 0, 0); \
  acc[mB][1] = MFMA16(av[mB], bv[1], acc[mB][1], 0, 0, 0); \
  acc[mB][2] = MFMA16(av[mB], bv[2], acc[mB][2], 0, 0, 0); \
  acc[mB][3] = MFMA16(av[mB], bv[3], acc[mB][3], 0, 0, 0);

#define SGB_MFMA __builtin_amdgcn_sched_group_barrier(0x8, 8, 0)
#define SGB_DS2  __builtin_amdgcn_sched_group_barrier(0x100, 2, 0)
#define SGB_DS6  __builtin_amdgcn_sched_group_barrier(0x100, 6, 0)

// par = p%4 (parity whose regs this phase consumes); reads target (par+1)&3.
#define PHASE(par, RD, STAGE_STMT, VMW_STMT) do { \
  STAGE_STMT; \
  VMW_STMT; \
  asm volatile("s_waitcnt lgkmcnt(0)" ::: "memory"); \
  __builtin_amdgcn_s_barrier(); \
  __builtin_amdgcn_sched_barrier(0); \
  __builtin_amdgcn_s_setprio(1); \
  const char* na_ = ldsc + LDSA(((par) + 1) & 3) + aob; \
  const char* nb_ = ldsc + LDSB(((par) + 1) & 3) + bob; \
  G8(0, 1); \
  if (RD) { av[0] = *(const bf16x8*)(na_); \
            av[1] = *(const bf16x8*)(na_ + 1024); } \
  G8(2, 3); \
  if (RD) { av[2] = *(const bf16x8*)(na_ + 2048); \
            av[3] = *(const bf16x8*)(na_ + 3072); } \
  G8(4, 5); \
  if (RD) { av[4] = *(const bf16x8*)(na_ + 4096); \
            av[5] = *(const bf16x8*)(na_ + 5120); } \
  G8(6, 7); \
  if (RD) { av[6] = *(const bf16x8*)(na_ + 6144); \
            av[7] = *(const bf16x8*)(na_ + 7168); \
            bv[0] = *(const bf16x8*)(nb_); \
            bv[1] = *(const bf16x8*)(nb_ + 1024); \
            bv[2] = *(const bf16x8*)(nb_ + 2048); \
            bv[3] = *(const bf16x8*)(nb_ + 3072); } \
  __builtin_amdgcn_s_setprio(0); \
  if (RD) { \
    SGB_MFMA; SGB_DS2; SGB_MFMA; SGB_DS2; \
    SGB_MFMA; SGB_DS2; SGB_MFMA; SGB_DS6; \
  } \
} while (0)

__global__ __launch_bounds__(512, 2) void lstm_gemm(const u16* __restrict__ A,
                                                    const u16* __restrict__ Wt,
                                                    const float* __restrict__ c_prev,
                                                    float* __restrict__ out) {
  __shared__ __align__(16) u16 lds[65536];   // 128 KiB
  char* ldsc = (char*)lds;
  const int tid  = threadIdx.x;
  const int lane = tid & 63;
  const int wid  = tid >> 6;
  const int wr   = wid >> 2;   // 0..1: 128-row slice
  const int wcn  = wid & 3;    // 0..3: 64-col slice (4 gates x 16 u)
  const int fr   = lane & 15;
  const int fq   = lane >> 4;

  // XCD-aware swizzle (512 % 8 == 0 -> bijective)
  const int orig = blockIdx.x;
  const int wg   = ((orig & 7) << 6) | (orig >> 3);
  const int bm   = wg & 15;
  const int bn   = wg >> 4;

  const u16* Ab = A  + (size_t)bm * 256 * K_;
  const u16* Bb = Wt + (size_t)bn * 256 * K_;

  // staging: thread -> (row, swizzled 16B chunk) of a [256][32] tile slice
  const int grow = tid >> 2;                                 // 0..127
  const int gch8 = (((tid & 3) ^ ((grow >> 1) & 3)) << 3);   // element offset
  // fragment reads: logical chunk fq at row r lives at fq ^ ((r>>1)&3)
  const int csw = (fq ^ ((fr >> 1) & 3)) << 4;
  const int aob = (wr * 128 + fr) * 64 + csw;   // + m*1024
  const int bob = (wcn * 64 + fr) * 64 + csw;   // + n*1024

  f32x4 acc[8][4] = {};   // [m-frag][gate]
  bf16x8 av[8], bv[4];

  // ---- prologue: tiles 0,1 staged; tile0 drained + frags read ----
  STAGE4(0, 0);
  STAGE4(1, 1);
  VMW(4);
  __builtin_amdgcn_s_barrier();
  {
    const char* pa_ = ldsc + LDSA(0) + aob;
    const char* pb_ = ldsc + LDSB(0) + bob;
#pragma unroll
    for (int m_ = 0; m_ < 8; ++m_) av[m_] = *(const bf16x8*)(pa_ + m_ * 1024);
#pragma unroll
    for (int n_ = 0; n_ < 4; ++n_) bv[n_] = *(const bf16x8*)(pb_ + n_ * 1024);
  }

  for (int tb = 0; tb < NT_; tb += 4) {
    PHASE(0, 1, { STAGE4(2, tb + 2); }, { VMW(4); });
    PHASE(1, 1, { STAGE4(3, tb + 3); }, { VMW(4); });
    if (tb + 4 < NT_) {
      PHASE(2, 1, { STAGE4(0, tb + 4); }, { VMW(4); });
      PHASE(3, 1, { STAGE4(1, tb + 5); }, { VMW(4); });
    } else {
      PHASE(2, 1, {}, { VMW(0); });
      PHASE(3, 0, {}, {});
    }
  }

  // ---- fused LSTM epilogue (C/D 16x16: col=fr, row=fq*4+r) ----
  const int u  = (bn * 4 + wcn) * 16 + fr;
  const size_t BU = (size_t)B_ * U_;
#pragma unroll
  for (int mi = 0; mi < 8; ++mi) {
#pragma unroll
    for (int r = 0; r < 4; ++r) {
      int row = bm * 256 + wr * 128 + mi * 16 + fq * 4 + r;
      float zi = acc[mi][0][r], zf = acc[mi][1][r];
      float zc = acc[mi][2][r], zo = acc[mi][3][r];
      float iv = hsig(zi), fv = hsig(zf), ov = hsig(zo);
      size_t off = (size_t)row * U_ + u;
      float cp = c_prev[off];
      float cv = fv * cp + iv * ftanh(zc);
      float hv = ov * ftanh(cv);
      out[off]          = hv;
      out[BU + off]     = hv;
      out[2 * BU + off] = cv;
    }
  }
}

extern "C" void kernel_launch(void* const* d_in, const int* in_sizes, int n_in,
                              void* d_out, int out_size, void* d_ws, size_t ws_size,
                              hipStream_t stream) {
  const float* x  = (const float*)d_in[0];
  const float* h  = (const float*)d_in[1];
  const float* cp = (const float*)d_in[2];
  const float* kk = (const float*)d_in[3];
  const float* rk = (const float*)d_in[4];
  float* out = (float*)d_out;

  const size_t bytesA  = (size_t)B_ * K_ * 2;   // 32 MiB
  const size_t bytesWt = (size_t)N_ * K_ * 2;   // 64 MiB
  if (ws_size < bytesA + bytesWt) return;

  u16* Aws = (u16*)d_ws;
  u16* Wt  = (u16*)((char*)d_ws + bytesA);

  cast_a<<<(B_ * K_ / 8) / 256, 256, 0, stream>>>(x, h, Aws);
  cast_wt<<<dim3(N_ / 64, K_ / 64), 256, 0, stream>>>(kk, rk, Wt);
  lstm_gemm<<<dim3(512), dim3(512), 0, stream>>>(Aws, Wt, cp, out);
}

// Round 9
// 1583.371 us; speedup vs baseline: 1.1767x; 1.1767x over previous
//
#include <hip/hip_runtime.h>
#include <stdint.h>

typedef unsigned short u16;
typedef float f32x4 __attribute__((ext_vector_type(4)));
typedef __bf16 bf16x8 __attribute__((ext_vector_type(8)));

#define B_ 4096
#define D_ 2048
#define U_ 2048
#define K_ 4096   // D + U
#define N_ 8192   // 4*U
#define NT_ 128   // K/32 K-tiles

__device__ __forceinline__ u16 f32_bf16(float f) {
  uint32_t u = __float_as_uint(f);
  u += 0x7FFFu + ((u >> 16) & 1u);
  return (u16)(u >> 16);
}
__device__ __forceinline__ float hsig(float x) {
  return fminf(fmaxf(0.2f * x + 0.5f, 0.0f), 1.0f);
}
__device__ __forceinline__ float ftanh(float x) {
  x = fminf(fmaxf(x, -15.0f), 15.0f);
  float e = __expf(2.0f * x);
  return (e - 1.0f) / (e + 1.0f);
}
__device__ __forceinline__ void gload16(const void* g, void* l) {
  __builtin_amdgcn_global_load_lds(
      (const __attribute__((address_space(1))) void*)g,
      (__attribute__((address_space(3))) void*)l,
      16, 0, 0);
}

// ---- cast A = [inputs | h_tm1] -> bf16 [4096][4096] ----
__global__ __launch_bounds__(256) void cast_a(const float* __restrict__ x,
                                              const float* __restrict__ h,
                                              u16* __restrict__ A) {
  int c = blockIdx.x * 256 + threadIdx.x;
  int m = c >> 9;
  int kc = (c & 511) << 3;
  const float* src = (kc < D_) ? (x + (size_t)m * D_ + kc)
                               : (h + (size_t)m * U_ + (kc - D_));
  float4 v0 = ((const float4*)src)[0];
  float4 v1 = ((const float4*)src)[1];
  u16 o[8] = { f32_bf16(v0.x), f32_bf16(v0.y), f32_bf16(v0.z), f32_bf16(v0.w),
               f32_bf16(v1.x), f32_bf16(v1.y), f32_bf16(v1.z), f32_bf16(v1.w) };
  *(uint4*)(A + (size_t)c * 8) = *(const uint4*)o;
}

// ---- cast + transpose + gate-interleave W -> Wt[n'][k] bf16 [8192][4096] ----
// n' = ublk*64 + g*16 + ul  where u = ublk*16 + ul, original col n = g*2048 + u
__global__ __launch_bounds__(256) void cast_wt(const float* __restrict__ kern,
                                               const float* __restrict__ rker,
                                               u16* __restrict__ Wt) {
  __shared__ u16 sW[64][68];
  const int t = threadIdx.x;
  const int bx = blockIdx.x;   // ublk 0..127
  const int by = blockIdx.y;   // k block 0..63
  const int k0 = by * 64;
  const float* src = (k0 < D_) ? kern : rker;
  const int krow0 = (k0 < D_) ? k0 : (k0 - D_);
#pragma unroll
  for (int i = 0; i < 4; ++i) {
    int c = i * 256 + t;
    int kl = c >> 4;
    int nq = c & 15;
    int g  = nq >> 2;
    int ul = (nq & 3) << 2;
    int n  = g * U_ + bx * 16 + ul;
    float4 v = *(const float4*)(src + (size_t)(krow0 + kl) * N_ + n);
    u16 p[4] = { f32_bf16(v.x), f32_bf16(v.y), f32_bf16(v.z), f32_bf16(v.w) };
    *(ushort4*)&sW[kl][g * 16 + ul] = *(const ushort4*)p;
  }
  __syncthreads();
#pragma unroll
  for (int j = 0; j < 2; ++j) {
    int c2 = j * 256 + t;
    int nl = c2 >> 3;
    int kc = c2 & 7;
    u16 p[8];
#pragma unroll
    for (int jj = 0; jj < 8; ++jj) p[jj] = sW[kc * 8 + jj][nl];
    *(uint4*)(Wt + ((size_t)bx * 64 + nl) * K_ + k0 + kc * 8) = *(const uint4*)p;
  }
}

// == 256x256 GEMM: 4-parity BK=32, double-buffered fragments, LDS||MFMA ==
// LDS: 4 parities x (A[256][32] 16K + B[256][32] 16K) = 128 KiB.
// phys_chunk = logical ^ ((row>>1)&3): measured 0-conflict (rounds 3/6).
//
// Phase p (consumes reg-set CUR = parity p, read during phase p-1):
//   STAGE tile p+2 -> parity (p+2)%4
//   VMW(4): drain stage(p-1) -> parity p+1 complete in LDS (this wave)
//   s_barrier        -> ALL waves' parity-(p+1) stages complete
//   asm "" memory    -> compiler fence: next reads cannot hoist above barrier
//   issue 12 ds_reads of parity p+1 -> reg-set NXT   (no explicit lgkm wait;
//       SIInsertWaitcnts emits minimal counted lgkmcnt before each MFMA use)
//   32 MFMA on CUR   (overlaps the in-flight NXT reads = the round-6 gap)
//
// Safety: (read-after-write) reads of parity p+1 are runtime-after barrier(p),
// which is after every wave's VMW(4) drain of its parity-(p+1) stage loads.
// (write-after-read) parity q re-staged at phase q+2, issued after
// barrier(q+1); q's reads (issued phase q-1) are lgkm-landed before the last
// MFMA of phase q issues, which precedes that wave reaching barrier(q+1).
#define LDSA(par) ((par) * 32768)
#define LDSB(par) ((par) * 32768 + 16384)

#define STAGE4(par, t) do { \
  const u16* ga_ = Ab + (size_t)grow * K_ + (t) * 32 + gch8; \
  const u16* gb_ = Bb + (size_t)grow * K_ + (t) * 32 + gch8; \
  char* la_ = ldsc + LDSA(par) + wid * 1024; \
  char* lb_ = ldsc + LDSB(par) + wid * 1024; \
  gload16(ga_, la_); \
  gload16(ga_ + (size_t)128 * K_, la_ + 8192); \
  gload16(gb_, lb_); \
  gload16(gb_ + (size_t)128 * K_, lb_ + 8192); \
} while (0)

#define VMW(n) asm volatile("s_waitcnt vmcnt(" #n ")" ::: "memory")
#define MFMA16 __builtin_amdgcn_mfma_f32_16x16x32_bf16

#define READF(avX, bvX, par) do { \
  const char* pa_ = ldsc + LDSA(par) + aob; \
  const char* pb_ = ldsc + LDSB(par) + bob; \
  bvX[0] = *(const bf16x8*)(pb_); \
  bvX[1] = *(const bf16x8*)(pb_ + 1024); \
  bvX[2] = *(const bf16x8*)(pb_ + 2048); \
  bvX[3] = *(const bf16x8*)(pb_ + 3072); \
  _Pragma("unroll") \
  for (int m_ = 0; m_ < 8; ++m_) avX[m_] = *(const bf16x8*)(pa_ + m_ * 1024); \
} while (0)

#define G8S(avX, bvX, mA, mB) \
  acc[mA][0] = MFMA16(avX[mA], bvX[0], acc[mA][0], 0, 0, 0); \
  acc[mA][1] = MFMA16(avX[mA], bvX[1], acc[mA][1], 0, 0, 0); \
  acc[mA][2] = MFMA16(avX[mA], bvX[2], acc[mA][2], 0, 0, 0); \
  acc[mA][3] = MFMA16(avX[mA], bvX[3], acc[mA][3], 0, 0, 0); \
  acc[mB][0] = MFMA16(avX[mB], bvX[0], acc[mB][0], 0, 0, 0); \
  acc[mB][1] = MFMA16(avX[mB], bvX[1], acc[mB][1], 0, 0, 0); \
  acc[mB][2] = MFMA16(avX[mB], bvX[2], acc[mB][2], 0, 0, 0); \
  acc[mB][3] = MFMA16(avX[mB], bvX[3], acc[mB][3], 0, 0, 0);

#define PHASE(avC, bvC, avN, bvN, parN, RD, STAGE_STMT, VMW_STMT) do { \
  STAGE_STMT; \
  VMW_STMT; \
  __builtin_amdgcn_s_barrier(); \
  asm volatile("" ::: "memory"); \
  if (RD) { READF(avN, bvN, parN); } \
  __builtin_amdgcn_s_setprio(1); \
  G8S(avC, bvC, 0, 1); \
  G8S(avC, bvC, 2, 3); \
  G8S(avC, bvC, 4, 5); \
  G8S(avC, bvC, 6, 7); \
  __builtin_amdgcn_s_setprio(0); \
} while (0)

__global__ __launch_bounds__(512, 2) void lstm_gemm(const u16* __restrict__ A,
                                                    const u16* __restrict__ Wt,
                                                    const float* __restrict__ c_prev,
                                                    float* __restrict__ out) {
  __shared__ __align__(16) u16 lds[65536];   // 128 KiB
  char* ldsc = (char*)lds;
  const int tid  = threadIdx.x;
  const int lane = tid & 63;
  const int wid  = tid >> 6;
  const int wr   = wid >> 2;   // 0..1: 128-row slice
  const int wcn  = wid & 3;    // 0..3: 64-col slice (4 gates x 16 u)
  const int fr   = lane & 15;
  const int fq   = lane >> 4;

  // XCD-aware swizzle (512 % 8 == 0 -> bijective)
  const int orig = blockIdx.x;
  const int wg   = ((orig & 7) << 6) | (orig >> 3);
  const int bm   = wg & 15;
  const int bn   = wg >> 4;

  const u16* Ab = A  + (size_t)bm * 256 * K_;
  const u16* Bb = Wt + (size_t)bn * 256 * K_;

  // staging: thread -> (row, swizzled 16B chunk) of a [256][32] tile slice
  const int grow = tid >> 2;                                 // 0..127
  const int gch8 = (((tid & 3) ^ ((grow >> 1) & 3)) << 3);   // element offset
  // fragment reads: logical chunk fq at row r lives at fq ^ ((r>>1)&3)
  const int csw = (fq ^ ((fr >> 1) & 3)) << 4;
  const int aob = (wr * 128 + fr) * 64 + csw;   // + m*1024
  const int bob = (wcn * 64 + fr) * 64 + csw;   // + n*1024

  f32x4 acc[8][4] = {};   // [m-frag][gate] -> AGPRs
  bf16x8 av0[8], bv0[4], av1[8], bv1[4];

  // ---- prologue: stage tiles 0,1; drain tile0; barrier; read parity 0 ----
  STAGE4(0, 0);
  STAGE4(1, 1);
  VMW(4);
  __builtin_amdgcn_s_barrier();
  asm volatile("" ::: "memory");
  READF(av0, bv0, 0);

  for (int tb = 0; tb < NT_; tb += 4) {
    PHASE(av0, bv0, av1, bv1, 1, 1, { STAGE4(2, tb + 2); }, { VMW(4); });
    PHASE(av1, bv1, av0, bv0, 2, 1, { STAGE4(3, tb + 3); }, { VMW(4); });
    if (tb + 4 < NT_) {
      PHASE(av0, bv0, av1, bv1, 3, 1, { STAGE4(0, tb + 4); }, { VMW(4); });
      PHASE(av1, bv1, av0, bv0, 0, 1, { STAGE4(1, tb + 5); }, { VMW(4); });
    } else {
      PHASE(av0, bv0, av1, bv1, 3, 1, {}, { VMW(0); });
      PHASE(av1, bv1, av0, bv0, 0, 0, {}, {});
    }
  }

  // ---- fused LSTM epilogue (C/D 16x16: col=fr, row=fq*4+r) ----
  const int u  = (bn * 4 + wcn) * 16 + fr;
  const size_t BU = (size_t)B_ * U_;
#pragma unroll
  for (int mi = 0; mi < 8; ++mi) {
#pragma unroll
    for (int r = 0; r < 4; ++r) {
      int row = bm * 256 + wr * 128 + mi * 16 + fq * 4 + r;
      float zi = acc[mi][0][r], zf = acc[mi][1][r];
      float zc = acc[mi][2][r], zo = acc[mi][3][r];
      float iv = hsig(zi), fv = hsig(zf), ov = hsig(zo);
      size_t off = (size_t)row * U_ + u;
      float cp = c_prev[off];
      float cv = fv * cp + iv * ftanh(zc);
      float hv = ov * ftanh(cv);
      out[off]          = hv;
      out[BU + off]     = hv;
      out[2 * BU + off] = cv;
    }
  }
}

extern "C" void kernel_launch(void* const* d_in, const int* in_sizes, int n_in,
                              void* d_out, int out_size, void* d_ws, size_t ws_size,
                              hipStream_t stream) {
  const float* x  = (const float*)d_in[0];
  const float* h  = (const float*)d_in[1];
  const float* cp = (const float*)d_in[2];
  const float* kk = (const float*)d_in[3];
  const float* rk = (const float*)d_in[4];
  float* out = (float*)d_out;

  const size_t bytesA  = (size_t)B_ * K_ * 2;   // 32 MiB
  const size_t bytesWt = (size_t)N_ * K_ * 2;   // 64 MiB
  if (ws_size < bytesA + bytesWt) return;

  u16* Aws = (u16*)d_ws;
  u16* Wt  = (u16*)((char*)d_ws + bytesA);

  cast_a<<<(B_ * K_ / 8) / 256, 256, 0, stream>>>(x, h, Aws);
  cast_wt<<<dim3(N_ / 64, K_ / 64), 256, 0, stream>>>(kk, rk, Wt);
  lstm_gemm<<<dim3(512), dim3(512), 0, stream>>>(Aws, Wt, cp, out);
}

// Round 10
// 434.726 us; speedup vs baseline: 4.2858x; 3.6422x over previous
//
#include <hip/hip_runtime.h>
#include <stdint.h>

typedef unsigned short u16;
typedef float f32x4 __attribute__((ext_vector_type(4)));
typedef __bf16 bf16x8 __attribute__((ext_vector_type(8)));

#define B_ 4096
#define D_ 2048
#define U_ 2048
#define K_ 4096   // D + U
#define N_ 8192   // 4*U
#define NT_ 128   // K/32 K-tiles

__device__ __forceinline__ u16 f32_bf16(float f) {
  uint32_t u = __float_as_uint(f);
  u += 0x7FFFu + ((u >> 16) & 1u);
  return (u16)(u >> 16);
}
__device__ __forceinline__ float hsig(float x) {
  return fminf(fmaxf(0.2f * x + 0.5f, 0.0f), 1.0f);
}
__device__ __forceinline__ float ftanh(float x) {
  x = fminf(fmaxf(x, -15.0f), 15.0f);
  float e = __expf(2.0f * x);
  return (e - 1.0f) / (e + 1.0f);
}
__device__ __forceinline__ void gload16(const void* g, void* l) {
  __builtin_amdgcn_global_load_lds(
      (const __attribute__((address_space(1))) void*)g,
      (__attribute__((address_space(3))) void*)l,
      16, 0, 0);
}

// ---- cast A = [inputs | h_tm1] -> bf16 [4096][4096] ----
__global__ __launch_bounds__(256) void cast_a(const float* __restrict__ x,
                                              const float* __restrict__ h,
                                              u16* __restrict__ A) {
  int c = blockIdx.x * 256 + threadIdx.x;
  int m = c >> 9;
  int kc = (c & 511) << 3;
  const float* src = (kc < D_) ? (x + (size_t)m * D_ + kc)
                               : (h + (size_t)m * U_ + (kc - D_));
  float4 v0 = ((const float4*)src)[0];
  float4 v1 = ((const float4*)src)[1];
  u16 o[8] = { f32_bf16(v0.x), f32_bf16(v0.y), f32_bf16(v0.z), f32_bf16(v0.w),
               f32_bf16(v1.x), f32_bf16(v1.y), f32_bf16(v1.z), f32_bf16(v1.w) };
  *(uint4*)(A + (size_t)c * 8) = *(const uint4*)o;
}

// ---- cast + transpose + gate-interleave W -> Wt[n'][k] bf16 [8192][4096] ----
// n' = ublk*64 + g*16 + ul  where u = ublk*16 + ul, original col n = g*2048 + u
__global__ __launch_bounds__(256) void cast_wt(const float* __restrict__ kern,
                                               const float* __restrict__ rker,
                                               u16* __restrict__ Wt) {
  __shared__ u16 sW[64][68];
  const int t = threadIdx.x;
  const int bx = blockIdx.x;   // ublk 0..127
  const int by = blockIdx.y;   // k block 0..63
  const int k0 = by * 64;
  const float* src = (k0 < D_) ? kern : rker;
  const int krow0 = (k0 < D_) ? k0 : (k0 - D_);
#pragma unroll
  for (int i = 0; i < 4; ++i) {
    int c = i * 256 + t;
    int kl = c >> 4;
    int nq = c & 15;
    int g  = nq >> 2;
    int ul = (nq & 3) << 2;
    int n  = g * U_ + bx * 16 + ul;
    float4 v = *(const float4*)(src + (size_t)(krow0 + kl) * N_ + n);
    u16 p[4] = { f32_bf16(v.x), f32_bf16(v.y), f32_bf16(v.z), f32_bf16(v.w) };
    *(ushort4*)&sW[kl][g * 16 + ul] = *(const ushort4*)p;
  }
  __syncthreads();
#pragma unroll
  for (int j = 0; j < 2; ++j) {
    int c2 = j * 256 + t;
    int nl = c2 >> 3;
    int kc = c2 & 7;
    u16 p[8];
#pragma unroll
    for (int jj = 0; jj < 8; ++jj) p[jj] = sW[kc * 8 + jj][nl];
    *(uint4*)(Wt + ((size_t)bx * 64 + nl) * K_ + k0 + kc * 8) = *(const uint4*)p;
  }
}

// == 256x128 GEMM, 4 waves (1/SIMD), 4-parity BK=32, dbuf frags, LDS||MFMA ==
// LDS: 4 parities x (A[256][32] 16K + B[128][32] 8K) = 96 KiB -> 1 block/CU,
// 4 waves/CU. __launch_bounds__(256,1) -> 512-reg cap: acc 128 + dbl frags 96
// + addr fits with huge headroom (round-9 spill eliminated by construction).
// Per phase per SIMD: 32 MFMA (592 cyc) || per CU 48 ds_read_b128 (576 cyc).
//
// Phase p (consumes reg-set CUR, read during phase p-1 from parity p):
//   STAGE tile p+2 -> parity (p+2)%4   (6 gloads)
//   VMW(6): <=6 outstanding -> stage(p-1) (parity p+1) landed, this wave
//   s_barrier -> all waves' parity-(p+1) stages landed
//   asm "" memory -> reads below cannot hoist above barrier (round-8 fix)
//   READF parity p+1 -> reg-set NXT (in flight; counted lgkm by compiler)
//   32 MFMA on CUR (overlap the NXT reads)
// WAR: parity q re-staged at phase q+2 after barrier(q+1); q's reads landed
// before phase q's MFMAs issue, which precede that wave's barrier(q+1).
#define LDSA(par) ((par) * 24576)
#define LDSB(par) ((par) * 24576 + 16384)

#define STAGE6(par, t) do { \
  const u16* ga_ = Ab + (size_t)grow * K_ + (t) * 32 + gch8; \
  const u16* gb_ = Bb + (size_t)grow * K_ + (t) * 32 + gch8; \
  char* la_ = ldsc + LDSA(par) + stoff; \
  char* lb_ = ldsc + LDSB(par) + stoff; \
  gload16(ga_,                    la_); \
  gload16(ga_ + (size_t)64 * K_,  la_ + 4096); \
  gload16(ga_ + (size_t)128 * K_, la_ + 8192); \
  gload16(ga_ + (size_t)192 * K_, la_ + 12288); \
  gload16(gb_,                    lb_); \
  gload16(gb_ + (size_t)64 * K_,  lb_ + 4096); \
} while (0)

#define VMW(n) asm volatile("s_waitcnt vmcnt(" #n ")" ::: "memory")
#define MFMA16 __builtin_amdgcn_mfma_f32_16x16x32_bf16

#define READF(avX, bvX, par) do { \
  const char* pa_ = ldsc + LDSA(par) + aob; \
  const char* pb_ = ldsc + LDSB(par) + bob; \
  bvX[0] = *(const bf16x8*)(pb_); \
  bvX[1] = *(const bf16x8*)(pb_ + 1024); \
  bvX[2] = *(const bf16x8*)(pb_ + 2048); \
  bvX[3] = *(const bf16x8*)(pb_ + 3072); \
  _Pragma("unroll") \
  for (int m_ = 0; m_ < 8; ++m_) avX[m_] = *(const bf16x8*)(pa_ + m_ * 1024); \
} while (0)

#define G8S(avX, bvX, mA, mB) \
  acc[mA][0] = MFMA16(avX[mA], bvX[0], acc[mA][0], 0, 0, 0); \
  acc[mA][1] = MFMA16(avX[mA], bvX[1], acc[mA][1], 0, 0, 0); \
  acc[mA][2] = MFMA16(avX[mA], bvX[2], acc[mA][2], 0, 0, 0); \
  acc[mA][3] = MFMA16(avX[mA], bvX[3], acc[mA][3], 0, 0, 0); \
  acc[mB][0] = MFMA16(avX[mB], bvX[0], acc[mB][0], 0, 0, 0); \
  acc[mB][1] = MFMA16(avX[mB], bvX[1], acc[mB][1], 0, 0, 0); \
  acc[mB][2] = MFMA16(avX[mB], bvX[2], acc[mB][2], 0, 0, 0); \
  acc[mB][3] = MFMA16(avX[mB], bvX[3], acc[mB][3], 0, 0, 0);

#define PHASE(avC, bvC, avN, bvN, parN, RD, STAGE_STMT, VMW_STMT) do { \
  STAGE_STMT; \
  VMW_STMT; \
  __builtin_amdgcn_s_barrier(); \
  asm volatile("" ::: "memory"); \
  if (RD) { READF(avN, bvN, parN); } \
  __builtin_amdgcn_s_setprio(1); \
  G8S(avC, bvC, 0, 1); \
  G8S(avC, bvC, 2, 3); \
  G8S(avC, bvC, 4, 5); \
  G8S(avC, bvC, 6, 7); \
  __builtin_amdgcn_s_setprio(0); \
} while (0)

__global__ __launch_bounds__(256, 1) void lstm_gemm(const u16* __restrict__ A,
                                                    const u16* __restrict__ Wt,
                                                    const float* __restrict__ c_prev,
                                                    float* __restrict__ out) {
  __shared__ __align__(16) u16 lds[49152];   // 96 KiB
  char* ldsc = (char*)lds;
  const int tid  = threadIdx.x;
  const int lane = tid & 63;
  const int wid  = tid >> 6;   // 0..3
  const int wr   = wid >> 1;   // 0..1: 128-row slice
  const int wcn  = wid & 1;    // 0..1: 64-col slice (4 gates x 16 u)
  const int fr   = lane & 15;
  const int fq   = lane >> 4;

  // XCD-aware swizzle (1024 % 8 == 0 -> bijective); bn fastest within an XCD
  // -> the XCD's 2 A-panels (4 MB) stay L2-resident across 64 bn values.
  const int orig = blockIdx.x;
  const int wg   = ((orig & 7) << 7) | (orig >> 3);
  const int bn   = wg & 63;    // 0..63 (cols of 128)
  const int bm   = wg >> 6;    // 0..15 (rows of 256)

  const u16* Ab = A  + (size_t)bm * 256 * K_;
  const u16* Bb = Wt + (size_t)bn * 128 * K_;

  // staging: thread -> (row grow, swizzled 16B chunk) of a [64][32] row-band
  const int grow  = tid >> 2;                                 // 0..63
  const int gch8  = (((tid & 3) ^ ((grow >> 1) & 3)) << 3);   // element offset
  const int stoff = wid * 1024;                               // LDS band base
  // fragment reads: logical chunk fq at row r lives at fq ^ ((r>>1)&3)
  const int csw = (fq ^ ((fr >> 1) & 3)) << 4;
  const int aob = (wr * 128 + fr) * 64 + csw;   // + m*1024
  const int bob = (wcn * 64 + fr) * 64 + csw;   // + n*1024

  f32x4 acc[8][4] = {};   // [m-frag][gate] -> AGPRs
  bf16x8 av0[8], bv0[4], av1[8], bv1[4];

  // ---- prologue: stage tiles 0,1; drain tile0; barrier; read parity 0 ----
  STAGE6(0, 0);
  STAGE6(1, 1);
  VMW(6);
  __builtin_amdgcn_s_barrier();
  asm volatile("" ::: "memory");
  READF(av0, bv0, 0);

  for (int tb = 0; tb < NT_; tb += 4) {
    PHASE(av0, bv0, av1, bv1, 1, 1, { STAGE6(2, tb + 2); }, { VMW(6); });
    PHASE(av1, bv1, av0, bv0, 2, 1, { STAGE6(3, tb + 3); }, { VMW(6); });
    if (tb + 4 < NT_) {
      PHASE(av0, bv0, av1, bv1, 3, 1, { STAGE6(0, tb + 4); }, { VMW(6); });
      PHASE(av1, bv1, av0, bv0, 0, 1, { STAGE6(1, tb + 5); }, { VMW(6); });
    } else {
      PHASE(av0, bv0, av1, bv1, 3, 1, {}, { VMW(0); });
      PHASE(av1, bv1, av0, bv0, 0, 0, {}, {});
    }
  }

  // ---- fused LSTM epilogue (C/D 16x16: col=fr, row=fq*4+r) ----
  const int u  = (bn * 2 + wcn) * 16 + fr;
  const size_t BU = (size_t)B_ * U_;
#pragma unroll
  for (int mi = 0; mi < 8; ++mi) {
#pragma unroll
    for (int r = 0; r < 4; ++r) {
      int row = bm * 256 + wr * 128 + mi * 16 + fq * 4 + r;
      float zi = acc[mi][0][r], zf = acc[mi][1][r];
      float zc = acc[mi][2][r], zo = acc[mi][3][r];
      float iv = hsig(zi), fv = hsig(zf), ov = hsig(zo);
      size_t off = (size_t)row * U_ + u;
      float cp = c_prev[off];
      float cv = fv * cp + iv * ftanh(zc);
      float hv = ov * ftanh(cv);
      out[off]          = hv;
      out[BU + off]     = hv;
      out[2 * BU + off] = cv;
    }
  }
}

extern "C" void kernel_launch(void* const* d_in, const int* in_sizes, int n_in,
                              void* d_out, int out_size, void* d_ws, size_t ws_size,
                              hipStream_t stream) {
  const float* x  = (const float*)d_in[0];
  const float* h  = (const float*)d_in[1];
  const float* cp = (const float*)d_in[2];
  const float* kk = (const float*)d_in[3];
  const float* rk = (const float*)d_in[4];
  float* out = (float*)d_out;

  const size_t bytesA  = (size_t)B_ * K_ * 2;   // 32 MiB
  const size_t bytesWt = (size_t)N_ * K_ * 2;   // 64 MiB
  if (ws_size < bytesA + bytesWt) return;

  u16* Aws = (u16*)d_ws;
  u16* Wt  = (u16*)((char*)d_ws + bytesA);

  cast_a<<<(B_ * K_ / 8) / 256, 256, 0, stream>>>(x, h, Aws);
  cast_wt<<<dim3(N_ / 64, K_ / 64), 256, 0, stream>>>(kk, rk, Wt);
  lstm_gemm<<<dim3(1024), dim3(256), 0, stream>>>(Aws, Wt, cp, out);
}